// Round 10
// baseline (307.306 us; speedup 1.0000x reference)
//
#include <hip/hip_runtime.h>
#include <cstddef>

constexpr int NN  = 40000;   // nodes
constexpr int NE  = 640000;  // edges
constexpr int DIM = 128;     // D_IN == D_OUT
constexpr int CAP = 48;      // per-node neighbor capacity
constexpr int PLANE = NN * 64;    // shorts per 64-dim plane
constexpr int GRID = 256;         // == #CUs; 1 block/CU worst-case -> all resident
constexpr int BLKT = 512;         // 8 waves
constexpr int NTHR = GRID * BLKT; // 131072 threads
constexpr int NWAVE = NTHR / 64;  // 2048 waves

// per-phase barrier magics (poison bytes never equal these; each phase
// overwrites the previous phase's value -> no init needed across replays)
constexpr unsigned int MG1 = 0x5a6e0001u;
constexpr unsigned int MG2 = 0x5a6e0002u;
constexpr unsigned int MG3 = 0x5a6e0003u;

typedef __attribute__((ext_vector_type(8))) short short8;   // 8 bf16
typedef __attribute__((ext_vector_type(4))) float floatx4;  // MFMA acc

__device__ __forceinline__ unsigned short f2bf(float x) {
    union { float f; unsigned int i; } v; v.f = x;
    unsigned int u = v.i;
    return (unsigned short)((u + 0x7fffu + ((u >> 16) & 1u)) >> 16);
}
__device__ __forceinline__ float bflo2f(unsigned int u) {
    union { unsigned int i; float f; } v; v.i = u << 16; return v.f;
}
__device__ __forceinline__ float bfhi2f(unsigned int u) {
    union { unsigned int i; float f; } v; v.i = u & 0xffff0000u; return v.f;
}

// ---------------------------------------------------------------------------
// Grid barrier (graph-capture-safe, no coop API).
// Residency is guaranteed by GRID==256 with 1-block/CU worst case, so the
// spin terminates; the bound (~0.3s) is a hang-proof fallback only.
// arrival: agent release fence + release-store magic; wait: wave0 polls all
// 256 flags (4/lane, __all vote, s_sleep backoff); exit: acquire fence.
// ---------------------------------------------------------------------------
__device__ __forceinline__ void gbar(unsigned int* flags, unsigned int magic) {
    __syncthreads();
    if (threadIdx.x == 0) {
        __threadfence();   // release: make this block's writes agent-visible
        __hip_atomic_store(flags + blockIdx.x, magic,
                           __ATOMIC_RELEASE, __HIP_MEMORY_SCOPE_AGENT);
    }
    if (threadIdx.x < 64) {
        int l = threadIdx.x;
        for (int spin = 0; spin < 2000000; ++spin) {
            unsigned int ok = 1u;
            #pragma unroll
            for (int q = 0; q < 4; ++q) {
                unsigned int v = __hip_atomic_load(
                    flags + q * 64 + l, __ATOMIC_RELAXED,
                    __HIP_MEMORY_SCOPE_AGENT);
                ok &= (unsigned int)(v == magic);
            }
            if (__all(ok)) break;
            __builtin_amdgcn_s_sleep(8);
        }
    }
    __syncthreads();
    __threadfence();       // acquire: drop stale cached lines
}

// ---------------------------------------------------------------------------
// Single fused kernel: P0 prep | P1 fill | P2 gather | P3 GEMM.
// r6/r7 instrumentation: per-dispatch boundary ~7-10us x 4 dominates the
// controllable budget; phase bodies are the proven multi-kernel versions.
// ---------------------------------------------------------------------------
__global__ __launch_bounds__(512, 2) void k_one(
    const float* __restrict__ feat, const int* __restrict__ src,
    const int* __restrict__ dst, const float* __restrict__ Wself,
    const float* __restrict__ Wneigh, const float* __restrict__ bself,
    const float* __restrict__ bneigh, unsigned short* __restrict__ featb,
    unsigned short* __restrict__ hnb, unsigned short* __restrict__ colf,
    unsigned short* __restrict__ Wc, int* __restrict__ cnt,
    unsigned int* __restrict__ flags, float* __restrict__ out)
{
    __shared__ unsigned short As[160 * 64];  // 20480 B
    __shared__ unsigned short Bs[128 * 64];  // 16384 B (36.9 KB total)

    int b = blockIdx.x, t = threadIdx.x;
    int gtid = b * BLKT + t;
    int lane = t & 63;

    // ---------------- P0: zero cnt, cast feat -> planes, cast W ------------
    for (int i = gtid; i < NN; i += NTHR) cnt[i] = 0;

    for (int idx8 = gtid; idx8 < NN * 16; idx8 += NTHR) {
        int n  = idx8 >> 4;
        int d0 = (idx8 & 15) << 3;
        const float4* fp =
            reinterpret_cast<const float4*>(feat + (size_t)n * DIM + d0);
        float4 v0 = fp[0], v1 = fp[1];
        unsigned int p0 = (unsigned int)f2bf(v0.x) | ((unsigned int)f2bf(v0.y) << 16);
        unsigned int p1 = (unsigned int)f2bf(v0.z) | ((unsigned int)f2bf(v0.w) << 16);
        unsigned int p2 = (unsigned int)f2bf(v1.x) | ((unsigned int)f2bf(v1.y) << 16);
        unsigned int p3 = (unsigned int)f2bf(v1.z) | ((unsigned int)f2bf(v1.w) << 16);
        int plane = d0 >> 6, off = d0 & 63;
        *reinterpret_cast<uint4*>(
            featb + (size_t)plane * PLANE + (size_t)n * 64 + off) =
            make_uint4(p0, p1, p2, p3);
    }

    if (gtid < 32768) {   // Wc[4][128][64]
        int c = gtid >> 13, n = (gtid >> 6) & 127, kp = gtid & 63;
        int k = c * 64 + kp;
        float w = (k < DIM) ? Wself[(size_t)k * DIM + n]
                            : Wneigh[(size_t)(k - DIM) * DIM + n];
        Wc[gtid] = f2bf(w);
    }
    gbar(flags, MG1);

    // ---------------- P1: adjacency fill (device-scope atomics) ------------
    for (int e = gtid; e < NE; e += NTHR) {
        int d = dst[e];
        int pos = atomicAdd(&cnt[d], 1);
        if (pos < CAP) colf[d * CAP + pos] = (unsigned short)src[e];
    }
    gbar(flags, MG2);

    // ---------------- P2: gather + mean (r4 proven body, 2048 waves) -------
    {
        const unsigned int* fb32 = reinterpret_cast<const unsigned int*>(featb);
        unsigned int* hnb32 = reinterpret_cast<unsigned int*>(hnb);
        int vb = (lane >> 5) * (NN * 32) + (lane & 31);
        for (int n = (gtid >> 6); n < NN; n += NWAVE) {
            int deg = cnt[n];
            int m = min(deg, CAP);
            int sv = (lane < m) ? (int)colf[n * CAP + lane] : 0;
            float ax0 = 0.f, ay0 = 0.f, ax1 = 0.f, ay1 = 0.f;
            int i = 0;
            for (; i + 7 < m; i += 8) {
                int s0 = __shfl(sv, i),     s1 = __shfl(sv, i + 1);
                int s2 = __shfl(sv, i + 2), s3 = __shfl(sv, i + 3);
                int s4 = __shfl(sv, i + 4), s5 = __shfl(sv, i + 5);
                int s6 = __shfl(sv, i + 6), s7 = __shfl(sv, i + 7);
                unsigned int u0 = fb32[vb + s0 * 32];
                unsigned int u1 = fb32[vb + s1 * 32];
                unsigned int u2 = fb32[vb + s2 * 32];
                unsigned int u3 = fb32[vb + s3 * 32];
                unsigned int u4 = fb32[vb + s4 * 32];
                unsigned int u5 = fb32[vb + s5 * 32];
                unsigned int u6 = fb32[vb + s6 * 32];
                unsigned int u7 = fb32[vb + s7 * 32];
                ax0 += bflo2f(u0); ay0 += bfhi2f(u0);
                ax1 += bflo2f(u1); ay1 += bfhi2f(u1);
                ax0 += bflo2f(u2); ay0 += bfhi2f(u2);
                ax1 += bflo2f(u3); ay1 += bfhi2f(u3);
                ax0 += bflo2f(u4); ay0 += bfhi2f(u4);
                ax1 += bflo2f(u5); ay1 += bfhi2f(u5);
                ax0 += bflo2f(u6); ay0 += bfhi2f(u6);
                ax1 += bflo2f(u7); ay1 += bfhi2f(u7);
            }
            for (; i + 3 < m; i += 4) {
                int s0 = __shfl(sv, i),     s1 = __shfl(sv, i + 1);
                int s2 = __shfl(sv, i + 2), s3 = __shfl(sv, i + 3);
                unsigned int u0 = fb32[vb + s0 * 32];
                unsigned int u1 = fb32[vb + s1 * 32];
                unsigned int u2 = fb32[vb + s2 * 32];
                unsigned int u3 = fb32[vb + s3 * 32];
                ax0 += bflo2f(u0); ay0 += bfhi2f(u0);
                ax1 += bflo2f(u1); ay1 += bfhi2f(u1);
                ax0 += bflo2f(u2); ay0 += bfhi2f(u2);
                ax1 += bflo2f(u3); ay1 += bfhi2f(u3);
            }
            for (; i < m; ++i) {
                int s0 = __shfl(sv, i);
                unsigned int u0 = fb32[vb + s0 * 32];
                ax0 += bflo2f(u0); ay0 += bfhi2f(u0);
            }
            float inv = 1.0f / fmaxf((float)deg, 1.0f);
            float ax = (ax0 + ax1) * inv, ay = (ay0 + ay1) * inv;
            hnb32[vb + n * 32] =
                (unsigned int)f2bf(ax) | ((unsigned int)f2bf(ay) << 16);
        }
    }
    gbar(flags, MG3);

    // ---------------- P3: GEMM (r0 proven 160-row-tile structure) ----------
    // 250 active blocks; all 8 waves stage, waves 0-4 compute 32 rows each.
    if (b < 250) {
        int w = t >> 6;
        int base_m = b * 160;
        floatx4 acc[2][8];
        #pragma unroll
        for (int a = 0; a < 2; ++a)
            #pragma unroll
            for (int q = 0; q < 8; ++q) acc[a][q] = (floatx4)0.f;

        for (int c = 0; c < 4; ++c) {
            const unsigned short* srcp =
                ((c < 2) ? featb + (size_t)c * PLANE
                         : hnb + (size_t)(c - 2) * PLANE) + (size_t)base_m * 64;
            #pragma unroll
            for (int it = 0; it < 3; ++it) {      // 1280 slots / 512 threads
                int slot = t + it * 512;
                if (slot < 1280)
                    __builtin_amdgcn_global_load_lds(
                        (const __attribute__((address_space(1))) unsigned int*)(srcp + slot * 8),
                        (__attribute__((address_space(3))) unsigned int*)(As + slot * 8),
                        16, 0, 0);
            }
            const unsigned short* bp = Wc + (size_t)c * 128 * 64;
            #pragma unroll
            for (int it = 0; it < 2; ++it) {      // 1024 slots / 512 threads
                int slot = t + it * 512;
                __builtin_amdgcn_global_load_lds(
                    (const __attribute__((address_space(1))) unsigned int*)(bp + slot * 8),
                    (__attribute__((address_space(3))) unsigned int*)(Bs + slot * 8),
                    16, 0, 0);
            }
            __syncthreads();

            if (w < 5) {
                #pragma unroll
                for (int s = 0; s < 2; ++s) {
                    int koff = s * 32 + (lane >> 4) * 8;
                    short8 af[2];
                    #pragma unroll
                    for (int mt = 0; mt < 2; ++mt) {
                        int m = w * 32 + mt * 16 + (lane & 15);
                        af[mt] = *reinterpret_cast<const short8*>(As + m * 64 + koff);
                    }
                    #pragma unroll
                    for (int nt = 0; nt < 8; ++nt) {
                        int n = nt * 16 + (lane & 15);
                        short8 bf = *reinterpret_cast<const short8*>(Bs + n * 64 + koff);
                        acc[0][nt] = __builtin_amdgcn_mfma_f32_16x16x32_bf16(
                            af[0], bf, acc[0][nt], 0, 0, 0);
                        acc[1][nt] = __builtin_amdgcn_mfma_f32_16x16x32_bf16(
                            af[1], bf, acc[1][nt], 0, 0, 0);
                    }
                }
            }
            __syncthreads();
        }

        if (w < 5) {
            // epilogue: C/D layout col = lane&15, row = (lane>>4)*4 + r
            int colb = lane & 15;
            int quad = lane >> 4;
            #pragma unroll
            for (int nt = 0; nt < 8; ++nt) {
                int col = nt * 16 + colb;
                float bb = bself[col] + bneigh[col];
                #pragma unroll
                for (int mt = 0; mt < 2; ++mt) {
                    #pragma unroll
                    for (int r = 0; r < 4; ++r) {
                        int row = base_m + w * 32 + mt * 16 + quad * 4 + r;
                        out[(size_t)row * DIM + col] = acc[mt][nt][r] + bb;
                    }
                }
            }
        }
    }
}

// ---------------------------------------------------------------------------
extern "C" void kernel_launch(void* const* d_in, const int* in_sizes, int n_in,
                              void* d_out, int out_size, void* d_ws, size_t ws_size,
                              hipStream_t stream)
{
    const float* feat   = (const float*)d_in[0];
    const int*   src    = (const int*)d_in[1];
    const int*   dst    = (const int*)d_in[2];
    const float* Wself  = (const float*)d_in[3];
    const float* bself  = (const float*)d_in[4];
    const float* Wneigh = (const float*)d_in[5];
    const float* bneigh = (const float*)d_in[6];
    float* out = (float*)d_out;

    // Workspace layout (bytes):
    //   featb [2][NN][64] bf16 @ 0           (10,240,000)
    //   hnb   [2][NN][64] bf16 @ 10,240,000  (10,240,000)
    //   colf  [NN][CAP]   u16  @ 20,480,000  ( 3,840,000)
    //   Wc    [4][128][64]bf16 @ 24,320,000  (    65,536)
    //   cnt   [NN]        i32  @ 24,385,536  (   160,000)
    //   flags [256]       u32  @ 24,545,536  (     1,024)
    // total 24,546,560 B
    char* ws = (char*)d_ws;
    unsigned short* featb = (unsigned short*)(ws);
    unsigned short* hnb   = (unsigned short*)(ws + 10240000);
    unsigned short* colf  = (unsigned short*)(ws + 20480000);
    unsigned short* Wc    = (unsigned short*)(ws + 24320000);
    int*            cnt   = (int*)(ws + 24385536);
    unsigned int*   flags = (unsigned int*)(ws + 24545536);

    k_one<<<GRID, BLKT, 0, stream>>>(
        feat, src, dst, Wself, Wneigh, bself, bneigh,
        featb, hnb, colf, Wc, cnt, flags, out);
}

// Round 11
// 149.352 us; speedup vs baseline: 2.0576x; 2.0576x over previous
//
#include <hip/hip_runtime.h>
#include <cstddef>

constexpr int NN  = 40000;   // nodes
constexpr int NE  = 640000;  // edges
constexpr int DIM = 128;     // D_IN == D_OUT
constexpr int PLANE = NN * 64;  // shorts per 64-dim plane

// replicated adjacency: 4 replicas x 16 slots (=64 lanes) + 16 overflow slots
constexpr int RREP   = 4;
constexpr int CAP_R  = 16;
constexpr int CAP_O  = 16;

typedef __attribute__((ext_vector_type(8))) short short8;   // 8 bf16 (4 VGPRs)
typedef __attribute__((ext_vector_type(4))) float floatx4;  // MFMA acc

// fp32 -> bf16 with round-to-nearest-even
__device__ __forceinline__ unsigned short f2bf(float x) {
    union { float f; unsigned int i; } v; v.f = x;
    unsigned int u = v.i;
    return (unsigned short)((u + 0x7fffu + ((u >> 16) & 1u)) >> 16);
}
__device__ __forceinline__ float bflo2f(unsigned int u) {   // low bf16 -> f32
    union { unsigned int i; float f; } v; v.i = u << 16; return v.f;
}
__device__ __forceinline__ float bfhi2f(unsigned int u) {   // high bf16 -> f32
    union { unsigned int i; float f; } v; v.i = u & 0xffff0000u; return v.f;
}

// ---------------------------------------------------------------------------
// Prep: [blocks 0..2499]     cast feat fp32 -> bf16 planes featb[2][NN][64]
//       [blocks 2500..2627]  transpose+cast W to Wc[4][128][64]
//       [blocks 2628..3917]  zero the padded counters (cntR 5.12MB + cntO)
// ---------------------------------------------------------------------------
__global__ __launch_bounds__(256) void k_prep(
    const float* __restrict__ feat, const float* __restrict__ Wself,
    const float* __restrict__ Wneigh, unsigned short* __restrict__ featb,
    unsigned short* __restrict__ Wc, uint4* __restrict__ czero)
{
    int b = blockIdx.x, t = threadIdx.x;
    if (b < 2500) {
        int idx8 = b * 256 + t;          // 640000 groups of 8 elements
        int n  = idx8 >> 4;              // 16 groups per row
        int d0 = (idx8 & 15) << 3;       // dim base 0,8,...,120
        const float4* fp =
            reinterpret_cast<const float4*>(feat + (size_t)n * DIM + d0);
        float4 v0 = fp[0], v1 = fp[1];
        unsigned int p0 = (unsigned int)f2bf(v0.x) | ((unsigned int)f2bf(v0.y) << 16);
        unsigned int p1 = (unsigned int)f2bf(v0.z) | ((unsigned int)f2bf(v0.w) << 16);
        unsigned int p2 = (unsigned int)f2bf(v1.x) | ((unsigned int)f2bf(v1.y) << 16);
        unsigned int p3 = (unsigned int)f2bf(v1.z) | ((unsigned int)f2bf(v1.w) << 16);
        int plane = d0 >> 6, off = d0 & 63;
        *reinterpret_cast<uint4*>(
            featb + (size_t)plane * PLANE + (size_t)n * 64 + off) =
            make_uint4(p0, p1, p2, p3);
    } else if (b < 2628) {
        int idx = (b - 2500) * 256 + t;  // 0..32767
        int c = idx >> 13, n = (idx >> 6) & 127, kp = idx & 63;
        int k = c * 64 + kp;
        float w = (k < DIM) ? Wself[(size_t)k * DIM + n]
                            : Wneigh[(size_t)(k - DIM) * DIM + n];
        Wc[idx] = f2bf(w);
    } else {
        int i = (b - 2628) * 256 + t;    // 330000 uint4 = 5,280,000 B
        if (i < 330000) czero[i] = make_uint4(0u, 0u, 0u, 0u);
    }
}

// ---------------------------------------------------------------------------
// Adjacency fill v4: padded+replicated counters.
// Mechanism (r10 closure of r1/r2/r6 evidence): old cnt[NN] packed 16
// counters/64B line -> 256 serialized atomics + cross-XCD line migration per
// line. cntR[(n*4+r)*8] = one counter per 32B: ~8 atomics/line, 4-way less
// same-address contention. Rare overflow (replica>16) goes to an exact
// overflow segment — capacity 64+16 >= max deg (~36), zero edge loss.
// ---------------------------------------------------------------------------
__global__ __launch_bounds__(256) void k_fill(
    const int* __restrict__ src, const int* __restrict__ dst,
    int* __restrict__ cntR, int* __restrict__ cntO,
    unsigned short* __restrict__ colf, unsigned short* __restrict__ colfO)
{
    int e = blockIdx.x * 256 + threadIdx.x;
    if (e < NE) {
        int d = dst[e];
        int r = e & 3;
        int pos = atomicAdd(&cntR[(d * 4 + r) * 8], 1);
        if (pos < CAP_R) {
            colf[d * 64 + r * 16 + pos] = (unsigned short)src[e];
        } else {
            int po = atomicAdd(&cntO[d], 1);
            if (po < CAP_O) colfO[d * 16 + po] = (unsigned short)src[e];
        }
    }
}

// ---------------------------------------------------------------------------
// Gather + mean v4: one wave per node over the 4x16 segmented colf.
// Slot lane: segment r=lane>>4, j=lane&15; validity ballot -> 64-bit mask;
// iterate set bits (ffsll) with 8-deep MLP batches — loop count = deg, same
// as the proven r4 gather. deg = sum of true replica counts (incl. overflow).
// ---------------------------------------------------------------------------
__global__ __launch_bounds__(256) void k_gather(
    const unsigned int* __restrict__ fb32,   // featb viewed as [2][NN][32] uint
    const int* __restrict__ cntR, const int* __restrict__ cntO,
    const unsigned short* __restrict__ colf,
    const unsigned short* __restrict__ colfO,
    unsigned int* __restrict__ hnb32)        // hnb viewed as [2][NN][32] uint
{
    int gtid = blockIdx.x * blockDim.x + threadIdx.x;
    int n = gtid >> 6;
    if (n >= NN) return;
    int lane = threadIdx.x & 63;

    // lane holds replica (lane&3)'s true count; quad-sum -> deg on all lanes
    int c_mine = cntR[(n * 4 + (lane & 3)) * 8];
    int s = c_mine;
    s += __shfl_xor(s, 1);
    s += __shfl_xor(s, 2);
    int deg = s;
    int c_r = __shfl(c_mine, lane >> 4);     // count of my slot's segment

    int sv = (int)colf[n * 64 + lane];       // my slot's src id (garbage if invalid)
    unsigned long long V = __ballot((lane & 15) < c_r);
    int nb = __popcll(V);

    int vb = (lane >> 5) * (NN * 32) + (lane & 31);   // plane base + lane offset
    float ax0 = 0.f, ay0 = 0.f, ax1 = 0.f, ay1 = 0.f;
    int i = 0;
    while (i + 7 < nb) {
        int k0 = __ffsll(V) - 1; V &= V - 1;
        int k1 = __ffsll(V) - 1; V &= V - 1;
        int k2 = __ffsll(V) - 1; V &= V - 1;
        int k3 = __ffsll(V) - 1; V &= V - 1;
        int k4 = __ffsll(V) - 1; V &= V - 1;
        int k5 = __ffsll(V) - 1; V &= V - 1;
        int k6 = __ffsll(V) - 1; V &= V - 1;
        int k7 = __ffsll(V) - 1; V &= V - 1;
        int s0 = __shfl(sv, k0), s1 = __shfl(sv, k1);
        int s2 = __shfl(sv, k2), s3 = __shfl(sv, k3);
        int s4 = __shfl(sv, k4), s5 = __shfl(sv, k5);
        int s6 = __shfl(sv, k6), s7 = __shfl(sv, k7);
        unsigned int u0 = fb32[vb + s0 * 32];
        unsigned int u1 = fb32[vb + s1 * 32];
        unsigned int u2 = fb32[vb + s2 * 32];
        unsigned int u3 = fb32[vb + s3 * 32];
        unsigned int u4 = fb32[vb + s4 * 32];
        unsigned int u5 = fb32[vb + s5 * 32];
        unsigned int u6 = fb32[vb + s6 * 32];
        unsigned int u7 = fb32[vb + s7 * 32];
        ax0 += bflo2f(u0); ay0 += bfhi2f(u0);
        ax1 += bflo2f(u1); ay1 += bfhi2f(u1);
        ax0 += bflo2f(u2); ay0 += bfhi2f(u2);
        ax1 += bflo2f(u3); ay1 += bfhi2f(u3);
        ax0 += bflo2f(u4); ay0 += bfhi2f(u4);
        ax1 += bflo2f(u5); ay1 += bfhi2f(u5);
        ax0 += bflo2f(u6); ay0 += bfhi2f(u6);
        ax1 += bflo2f(u7); ay1 += bfhi2f(u7);
        i += 8;
    }
    while (i < nb) {
        int k0 = __ffsll(V) - 1; V &= V - 1;
        int s0 = __shfl(sv, k0);
        unsigned int u0 = fb32[vb + s0 * 32];
        ax0 += bflo2f(u0); ay0 += bfhi2f(u0);
        ++i;
    }

    // overflow segment (wave-uniform; ~never taken)
    int co = min(cntO[n], CAP_O);
    if (co > 0) {
        int svO = (lane < co) ? (int)colfO[n * 16 + lane] : 0;
        for (int q = 0; q < co; ++q) {
            int s0 = __shfl(svO, q);
            unsigned int u0 = fb32[vb + s0 * 32];
            ax0 += bflo2f(u0); ay0 += bfhi2f(u0);
        }
    }

    float inv = 1.0f / fmaxf((float)deg, 1.0f);
    float ax = (ax0 + ax1) * inv, ay = (ay0 + ay1) * inv;
    hnb32[vb + n * 32] = (unsigned int)f2bf(ax) | ((unsigned int)f2bf(ay) << 16);
}

// ---------------------------------------------------------------------------
// Fused GEMM (r4 proven form, source-swizzled LDS staging) — 148.3us config.
// ---------------------------------------------------------------------------
__global__ __launch_bounds__(320) void k_gemm(
    const unsigned short* __restrict__ featb,  // [2][NN][64]
    const unsigned short* __restrict__ hnb,    // [2][NN][64]
    const unsigned short* __restrict__ Wc,     // [4][128][64]
    const float* __restrict__ bself, const float* __restrict__ bneigh,
    float* __restrict__ out)                   // [NN,128] fp32
{
    __shared__ unsigned short As[160 * 64];  // 20480 B
    __shared__ unsigned short Bs[128 * 64];  // 16384 B

    int t = threadIdx.x;
    int w = t >> 6;
    int lane = t & 63;
    int base_m = blockIdx.x * 160;

    floatx4 acc[2][8];
    #pragma unroll
    for (int a = 0; a < 2; ++a)
        #pragma unroll
        for (int b = 0; b < 8; ++b) acc[a][b] = (floatx4)0.f;

    for (int c = 0; c < 4; ++c) {
        const unsigned short* srcp =
            ((c < 2) ? featb + (size_t)c * PLANE
                     : hnb + (size_t)(c - 2) * PLANE) + (size_t)base_m * 64;
        #pragma unroll
        for (int it = 0; it < 4; ++it) {          // 1280 slots / 320 threads
            int s = t + it * 320;
            int m = s >> 3, g = s & 7;            // LDS (row m, 16B-granule g)
            const unsigned short* sa = srcp + m * 64 + ((g ^ (m & 7)) << 3);
            __builtin_amdgcn_global_load_lds(
                (const __attribute__((address_space(1))) unsigned int*)sa,
                (__attribute__((address_space(3))) unsigned int*)(As + s * 8),
                16, 0, 0);
        }
        if (t < 256) {
            const unsigned short* bp = Wc + (size_t)c * 128 * 64;
            #pragma unroll
            for (int it = 0; it < 4; ++it) {      // 1024 slots / 256 threads
                int s = t + it * 256;
                int n = s >> 3, g = s & 7;
                const unsigned short* sb = bp + n * 64 + ((g ^ (n & 7)) << 3);
                __builtin_amdgcn_global_load_lds(
                    (const __attribute__((address_space(1))) unsigned int*)sb,
                    (__attribute__((address_space(3))) unsigned int*)(Bs + s * 8),
                    16, 0, 0);
            }
        }
        __syncthreads();

        #pragma unroll
        for (int sstep = 0; sstep < 2; ++sstep) {
            int gk = sstep * 4 + (lane >> 4);     // source 16B-granule wanted
            short8 af[2];
            #pragma unroll
            for (int mt = 0; mt < 2; ++mt) {
                int m = w * 32 + mt * 16 + (lane & 15);
                af[mt] = *reinterpret_cast<const short8*>(
                    As + m * 64 + ((gk ^ (m & 7)) << 3));
            }
            #pragma unroll
            for (int nt = 0; nt < 8; ++nt) {
                int n = nt * 16 + (lane & 15);
                short8 bf = *reinterpret_cast<const short8*>(
                    Bs + n * 64 + ((gk ^ (n & 7)) << 3));
                acc[0][nt] = __builtin_amdgcn_mfma_f32_16x16x32_bf16(
                    af[0], bf, acc[0][nt], 0, 0, 0);
                acc[1][nt] = __builtin_amdgcn_mfma_f32_16x16x32_bf16(
                    af[1], bf, acc[1][nt], 0, 0, 0);
            }
        }
        __syncthreads();
    }

    int colb = lane & 15;
    int quad = lane >> 4;
    #pragma unroll
    for (int nt = 0; nt < 8; ++nt) {
        int col = nt * 16 + colb;
        float bb = bself[col] + bneigh[col];
        #pragma unroll
        for (int mt = 0; mt < 2; ++mt) {
            #pragma unroll
            for (int r = 0; r < 4; ++r) {
                int row = base_m + w * 32 + mt * 16 + quad * 4 + r;
                out[(size_t)row * DIM + col] = acc[mt][nt][r] + bb;
            }
        }
    }
}

// ---------------------------------------------------------------------------
extern "C" void kernel_launch(void* const* d_in, const int* in_sizes, int n_in,
                              void* d_out, int out_size, void* d_ws, size_t ws_size,
                              hipStream_t stream)
{
    const float* feat   = (const float*)d_in[0];
    const int*   src    = (const int*)d_in[1];
    const int*   dst    = (const int*)d_in[2];
    const float* Wself  = (const float*)d_in[3];
    const float* bself  = (const float*)d_in[4];
    const float* Wneigh = (const float*)d_in[5];
    const float* bneigh = (const float*)d_in[6];
    float* out = (float*)d_out;

    // Workspace layout (bytes):
    //   featb [2][NN][64] bf16 @ 0           (10,240,000)
    //   hnb   [2][NN][64] bf16 @ 10,240,000  (10,240,000)
    //   colf  [NN][4][16] u16  @ 20,480,000  ( 5,120,000)
    //   colfO [NN][16]    u16  @ 25,600,000  ( 1,280,000)
    //   Wc    [4][128][64]bf16 @ 26,880,000  (    65,536)
    //   cntR  [NN][4] pad8 i32 @ 26,945,536  ( 5,120,000)
    //   cntO  [NN]        i32  @ 32,065,536  (   160,000)
    // total 32,225,536 B  (cntR+cntO zeroed contiguously: 5,280,000 B)
    char* ws = (char*)d_ws;
    unsigned short* featb = (unsigned short*)(ws);
    unsigned short* hnb   = (unsigned short*)(ws + 10240000);
    unsigned short* colf  = (unsigned short*)(ws + 20480000);
    unsigned short* colfO = (unsigned short*)(ws + 25600000);
    unsigned short* Wc    = (unsigned short*)(ws + 26880000);
    int*            cntR  = (int*)(ws + 26945536);
    int*            cntO  = (int*)(ws + 32065536);

    k_prep<<<3918, 256, 0, stream>>>(feat, Wself, Wneigh, featb, Wc,
                                     (uint4*)(ws + 26945536));

    k_fill<<<2500, 256, 0, stream>>>(src, dst, cntR, cntO, colf, colfO);

    k_gather<<<(NN * 64) / 256, 256, 0, stream>>>(
        (const unsigned int*)featb, cntR, cntO, colf, colfO,
        (unsigned int*)hnb);

    k_gemm<<<NN / 160, 320, 0, stream>>>(featb, hnb, Wc, bself, bneigh, out);
}